// Round 5
// baseline (152.991 us; speedup 1.0000x reference)
//
#include <hip/hip_runtime.h>
#include <hip/hip_bf16.h>

typedef __attribute__((ext_vector_type(8))) short bf16x8;
typedef __attribute__((ext_vector_type(4))) float f32x4;

#define CO    256
#define CI    2048
#define BATCH 8
#define HW    1024
#define NTOT  (BATCH * CI * HW)

#define BK    32
#define BHW   32
#define LDSA  40
#define LDSB  40

static __device__ __forceinline__ float fabs4max(const float4 v) {
  return fmaxf(fmaxf(fabsf(v.x), fabsf(v.y)), fmaxf(fabsf(v.z), fabsf(v.w)));
}

static __device__ __forceinline__ short f32_to_bf16_bits(float f) {
  return (short)(__float_as_uint(f) >> 16);
}

static __device__ __forceinline__ short quant1(float v, float inv_s) {
  return f32_to_bf16_bits(fminf(fmaxf(rintf(v * inv_s), -128.0f), 127.0f));
}

__global__ __launch_bounds__(256) void absmax_kernel(const float* __restrict__ x,
                                                     unsigned int* __restrict__ absbits,
                                                     long long n4) {
  long long i = (long long)blockIdx.x * blockDim.x + threadIdx.x;
  const long long stride = (long long)gridDim.x * blockDim.x;
  const float4* x4 = (const float4*)x;
  float m0 = 0.0f, m1 = 0.0f;
  for (; i + stride < n4; i += 2 * stride) {
    m0 = fmaxf(m0, fabs4max(x4[i]));
    m1 = fmaxf(m1, fabs4max(x4[i + stride]));
  }
  if (i < n4) m0 = fmaxf(m0, fabs4max(x4[i]));
  float m = fmaxf(m0, m1);
#pragma unroll
  for (int off = 32; off; off >>= 1) m = fmaxf(m, __shfl_xor(m, off));
  __shared__ float red[4];
  if ((threadIdx.x & 63) == 0) red[threadIdx.x >> 6] = m;
  __syncthreads();
  if (threadIdx.x == 0) {
    m = fmaxf(fmaxf(red[0], red[1]), fmaxf(red[2], red[3]));
    atomicMax(absbits, __float_as_uint(m));
  }
}

__global__ __launch_bounds__(256) void wquant_kernel(const float* __restrict__ w,
                                                     const float* __restrict__ bias,
                                                     const unsigned int* __restrict__ absbits,
                                                     short* __restrict__ qw,
                                                     float* __restrict__ alpha,
                                                     float* __restrict__ beta) {
  const int co = blockIdx.x;
  const int t = threadIdx.x;
  const float* row = w + (size_t)co * CI;
  const float4 v0 = ((const float4*)row)[t * 2];
  const float4 v1 = ((const float4*)row)[t * 2 + 1];
  float m = fmaxf(fabs4max(v0), fabs4max(v1));
#pragma unroll
  for (int off = 32; off; off >>= 1) m = fmaxf(m, __shfl_xor(m, off));
  __shared__ float red[4];
  __shared__ float s_sw;
  if ((t & 63) == 0) red[t >> 6] = m;
  __syncthreads();
  if (t == 0) {
    const float mm = fmaxf(fmaxf(red[0], red[1]), fmaxf(red[2], red[3]));
    s_sw = fmaxf(mm, 1e-8f) / 127.0f;
  }
  __syncthreads();
  const float sw = s_sw;

  const float vals[8] = {v0.x, v0.y, v0.z, v0.w, v1.x, v1.y, v1.z, v1.w};
  bf16x8 qv;
#pragma unroll
  for (int j = 0; j < 8; ++j) {
    const float q = fminf(fmaxf(rintf(vals[j] / sw), -128.0f), 127.0f);
    qv[j] = f32_to_bf16_bits(q);
  }
  *(bf16x8*)(qw + (size_t)co * CI + t * 8) = qv;

  if (t == 0) {
    const float sa = fmaxf(__uint_as_float(*absbits), 1e-8f) / 127.0f;
    const float a = sa * sw;
    alpha[co] = a;
    beta[co] = rintf(bias[co] / a) * a;
  }
}

// swapped-operand GEMM: D[r=hw][c=co]; block = co 256 x hw 32; 512 thr = 8 waves
__global__ __launch_bounds__(512) void gemm_kernel(const float* __restrict__ x,
                                                   const short* __restrict__ qw,
                                                   const float* __restrict__ alpha,
                                                   const float* __restrict__ beta,
                                                   const unsigned int* __restrict__ absbits,
                                                   float* __restrict__ out) {
  __shared__ short As[CO * LDSA];    // qw tile [co=256][k=32]
  __shared__ short Bs[BHW * LDSB];   // qx tile [hw=32][k=32]

  const int hwt = blockIdx.x & 31;
  const int b = blockIdx.x >> 5;
  const int hw0 = hwt * BHW;

  const float sa = fmaxf(__uint_as_float(*absbits), 1e-8f) / 127.0f;
  const float inv_sa = 1.0f / sa;

  const int t = threadIdx.x;
  const int lane = t & 63;
  const int w = t >> 6;
  const int wco = (w & 3) * 64;
  const int whw = (w >> 2) * 16;
  const int lr = lane & 15;
  const int kg = lane >> 4;

  const int arow = t >> 1;
  const int ak = (t & 1) * 16;
  const int bk = t >> 4;
  const int bhw = (t & 15) * 2;

  const short* ap0 = qw + (size_t)arow * CI + ak;
  const float* xp0 = x + ((size_t)b * CI + bk) * HW + hw0 + bhw;

  f32x4 acc[4] = {};

  bf16x8 av0 = *(const bf16x8*)(ap0);
  bf16x8 av1 = *(const bf16x8*)(ap0 + 8);
  float2 xv = *(const float2*)(xp0);

  for (int k0 = 0; k0 < CI; k0 += BK) {
    __syncthreads();
    *(bf16x8*)&As[arow * LDSA + ak] = av0;
    *(bf16x8*)&As[arow * LDSA + ak + 8] = av1;
    Bs[bhw * LDSB + bk] = quant1(xv.x, inv_sa);
    Bs[(bhw + 1) * LDSB + bk] = quant1(xv.y, inv_sa);

    const int kn = (k0 + BK) & (CI - 1);
    av0 = *(const bf16x8*)(ap0 + kn);
    av1 = *(const bf16x8*)(ap0 + kn + 8);
    xv = *(const float2*)(xp0 + (size_t)kn * HW);

    __syncthreads();

    const bf16x8 aF = *(const bf16x8*)&Bs[(whw + lr) * LDSB + kg * 8];
#pragma unroll
    for (int n = 0; n < 4; ++n) {
      const bf16x8 bF = *(const bf16x8*)&As[(wco + n * 16 + lr) * LDSA + kg * 8];
      acc[n] = __builtin_amdgcn_mfma_f32_16x16x32_bf16(aF, bF, acc[n], 0, 0, 0);
    }
  }

  const int hwo = hw0 + whw + kg * 4;
#pragma unroll
  for (int n = 0; n < 4; ++n) {
    const int co = wco + n * 16 + lr;
    const float af = alpha[co];
    const float bf = beta[co];
    float4 v;
    v.x = acc[n][0] * af + bf;
    v.y = acc[n][1] * af + bf;
    v.z = acc[n][2] * af + bf;
    v.w = acc[n][3] * af + bf;
    *(float4*)(out + ((size_t)(b * CO + co)) * HW + hwo) = v;
  }
}

extern "C" void kernel_launch(void* const* d_in, const int* in_sizes, int n_in,
                              void* d_out, int out_size, void* d_ws, size_t ws_size,
                              hipStream_t stream) {
  const float* x    = (const float*)d_in[0];
  const float* wgt  = (const float*)d_in[1];
  const float* bias = (const float*)d_in[2];
  float* out = (float*)d_out;

  unsigned int* absbits = (unsigned int*)d_ws;
  short* qw    = (short*)((char*)d_ws + 256);
  float* alpha = (float*)((char*)d_ws + 256 + (size_t)CO * CI * 2);
  float* beta  = alpha + CO;

  hipMemsetAsync(d_ws, 0, 4, stream);
  absmax_kernel<<<2048, 256, 0, stream>>>(x, absbits, (long long)(NTOT / 4));
  wquant_kernel<<<CO, 256, 0, stream>>>(wgt, bias, absbits, qw, alpha, beta);
  gemm_kernel<<<BATCH * 32, 512, 0, stream>>>(x, qw, alpha, beta, absbits, out);
}